// Round 1
// baseline (13277.922 us; speedup 1.0000x reference)
//
#include <hip/hip_runtime.h>
#include <math.h>

#define N_PTS 16384
#define M_CTR 4096
#define NS 16
#define CIN 64
#define COUT 128
#define CFEAT 67
#define CPB 4          // centers per block in passA
#define TS 2048        // kNN LDS tile

// ---------------- FPS: single block, dists in registers ----------------
__global__ __launch_bounds__(1024) void fps_kernel(const float* __restrict__ p,
                                                   int* __restrict__ sel)
{
    const int tid  = threadIdx.x;
    const int lane = tid & 63;
    const int wave = tid >> 6;

    float px[16], py[16], pz[16], dist[16];
#pragma unroll
    for (int k = 0; k < 16; ++k) {
        int j = tid + (k << 10);
        px[k] = p[j*3+0]; py[k] = p[j*3+1]; pz[k] = p[j*3+2];
        dist[k] = 1e10f;
    }

    __shared__ float sv[2][16];
    __shared__ int   si[2][16];

    int last = 0;
    if (tid == 0) sel[0] = 0;

    for (int it = 1; it < M_CTR; ++it) {
        float qx = p[last*3+0];
        float qy = p[last*3+1];
        float qz = p[last*3+2];

        float bv = -1.0f; int bi = 0;
#pragma unroll
        for (int k = 0; k < 16; ++k) {
            float dx = __fsub_rn(px[k], qx);
            float dy = __fsub_rn(py[k], qy);
            float dz = __fsub_rn(pz[k], qz);
            float d2 = __fadd_rn(__fadd_rn(__fmul_rn(dx,dx), __fmul_rn(dy,dy)),
                                 __fmul_rn(dz,dz));
            float nd = fminf(dist[k], d2);
            dist[k] = nd;
            bool b = nd > bv;            // strict: keeps lowest k (lowest idx) on tie
            bv = b ? nd : bv;
            bi = b ? (tid + (k<<10)) : bi;
        }
        // wave-level lexicographic argmax (max v, tie -> min idx)
#pragma unroll
        for (int m = 1; m < 64; m <<= 1) {
            float ov = __shfl_xor(bv, m);
            int   oi = __shfl_xor(bi, m);
            bool b = (ov > bv) || (ov == bv && oi < bi);
            bv = b ? ov : bv;
            bi = b ? oi : bi;
        }
        int buf = it & 1;
        if (lane == 0) { sv[buf][wave] = bv; si[buf][wave] = bi; }
        __syncthreads();
        bv = sv[buf][lane & 15];
        bi = si[buf][lane & 15];
#pragma unroll
        for (int m = 1; m < 16; m <<= 1) {
            float ov = __shfl_xor(bv, m);
            int   oi = __shfl_xor(bi, m);
            bool b = (ov > bv) || (ov == bv && oi < bi);
            bv = b ? ov : bv;
            bi = b ? oi : bi;
        }
        last = bi;
        if (tid == 0) sel[it] = bi;
    }
}

// ---------------- prep: pp2, gather n_p/n_n, write n_o ----------------
__global__ void prep_kernel(const float* __restrict__ p, const float* __restrict__ nrm,
                            const int* __restrict__ sel, float* __restrict__ pp2,
                            float* __restrict__ out)
{
    int i = blockIdx.x * blockDim.x + threadIdx.x;
    if (i < N_PTS) {
        float x = p[i*3], y = p[i*3+1], z = p[i*3+2];
        pp2[i] = __fadd_rn(__fadd_rn(__fmul_rn(x,x), __fmul_rn(y,y)), __fmul_rn(z,z));
    }
    if (i < M_CTR) {
        int j = sel[i];
        out[i*3+0] = p[j*3+0]; out[i*3+1] = p[j*3+1]; out[i*3+2] = p[j*3+2];
        out[12288 + i*3+0] = nrm[j*3+0];
        out[12288 + i*3+1] = nrm[j*3+1];
        out[12288 + i*3+2] = nrm[j*3+2];
    }
    if (i == 0) out[548864] = (float)M_CTR;   // n_o
}

// ---------------- kNN: one thread per center, LDS point tiles ----------------
__global__ __launch_bounds__(256) void knn_kernel(const float* __restrict__ p,
                                                  const float* __restrict__ pp2,
                                                  const float* __restrict__ out /* n_p */,
                                                  int* __restrict__ knn)
{
    __shared__ float sx[TS], sy[TS], sz[TS], s2[TS];
    const int t = threadIdx.x;
    const int center = blockIdx.x * 256 + t;
    float cx = out[center*3], cy = out[center*3+1], cz = out[center*3+2];
    float c2 = __fadd_rn(__fadd_rn(__fmul_rn(cx,cx), __fmul_rn(cy,cy)), __fmul_rn(cz,cz));

    float hv[16]; int hidx[16];
#pragma unroll
    for (int k = 0; k < 16; ++k) { hv[k] = 1e30f; hidx[k] = 0x7fffffff; }
    float wv = 1e30f; int wi = 0x7fffffff; int wslot = 0;

    for (int tile = 0; tile < N_PTS/TS; ++tile) {
        int base = tile * TS;
        for (int i = t; i < TS; i += 256) {
            sx[i] = p[(base+i)*3+0];
            sy[i] = p[(base+i)*3+1];
            sz[i] = p[(base+i)*3+2];
            s2[i] = pp2[base+i];
        }
        __syncthreads();
        for (int j = 0; j < TS; ++j) {
            float dot = __fadd_rn(__fadd_rn(__fmul_rn(cx,sx[j]), __fmul_rn(cy,sy[j])),
                                  __fmul_rn(cz,sz[j]));
            float d2  = __fsub_rn(__fadd_rn(c2, s2[j]), __fmul_rn(2.0f, dot));
            if (d2 < wv) {   // ascending idx scan: tie keeps stored (lower) idx
                int gi = base + j;
#pragma unroll
                for (int k = 0; k < 16; ++k) if (k == wslot) { hv[k] = d2; hidx[k] = gi; }
                wv = -1.0f; wi = -1; wslot = 0;
#pragma unroll
                for (int k = 0; k < 16; ++k) {
                    bool b = (hv[k] > wv) || (hv[k] == wv && hidx[k] > wi);
                    wv = b ? hv[k] : wv; wi = b ? hidx[k] : wi; wslot = b ? k : wslot;
                }
            }
        }
        __syncthreads();
    }
#pragma unroll
    for (int k = 0; k < 16; ++k) knn[center*16 + k] = hidx[k];
}

// ---------------- pass A: feat build + GEMM + stats + ymax/ymin ----------------
__global__ __launch_bounds__(128) void passA_kernel(const float* __restrict__ p,
                                                    const float* __restrict__ xf,
                                                    const float* __restrict__ W,
                                                    const int* __restrict__ knn,
                                                    const float* __restrict__ out /* n_p */,
                                                    float* __restrict__ ymax,   /* d_out y region */
                                                    float* __restrict__ ymin,
                                                    float* __restrict__ partials)
{
    __shared__ float Wt[CFEAT][COUT];          // 34304 B
    __shared__ float ft[CPB][NS][CFEAT];       // 17152 B
    __shared__ float bsum[CPB][COUT], bssq[CPB][COUT];  // 4 KB

    const int t = threadIdx.x;
    const int mbase = blockIdx.x * CPB;

    // stage W transposed: thread t owns output row t
    for (int c = 0; c < CFEAT; ++c) Wt[c][t] = W[t*CFEAT + c];

    // build features: 64 rows, 2 threads per row
    {
        int r = t >> 1, half = t & 1;
        int ci = r >> 4, s = r & 15;
        int m = mbase + ci;
        int nb = knn[m*NS + s];
        if (half == 0) {
            ft[ci][s][0] = __fsub_rn(p[nb*3+0], out[m*3+0]);
            ft[ci][s][1] = __fsub_rn(p[nb*3+1], out[m*3+1]);
            ft[ci][s][2] = __fsub_rn(p[nb*3+2], out[m*3+2]);
        }
        for (int c = half*32; c < half*32 + 32; ++c)
            ft[ci][s][3+c] = xf[nb*CIN + c];
    }
    __syncthreads();

    const int ci = t >> 5, l = t & 31;
    float acc[NS][4];
#pragma unroll
    for (int s = 0; s < NS; ++s) { acc[s][0]=0.f; acc[s][1]=0.f; acc[s][2]=0.f; acc[s][3]=0.f; }

    for (int c = 0; c < CFEAT; ++c) {
        float w0 = Wt[c][l], w1 = Wt[c][l+32], w2 = Wt[c][l+64], w3 = Wt[c][l+96];
#pragma unroll
        for (int s = 0; s < NS; ++s) {
            float f = ft[ci][s][c];
            acc[s][0] = fmaf(f, w0, acc[s][0]);
            acc[s][1] = fmaf(f, w1, acc[s][1]);
            acc[s][2] = fmaf(f, w2, acc[s][2]);
            acc[s][3] = fmaf(f, w3, acc[s][3]);
        }
    }

    const int m = mbase + ci;
#pragma unroll
    for (int j = 0; j < 4; ++j) {
        int o = l + 32*j;
        float s = 0.f, q = 0.f, mx = -1e30f, mn = 1e30f;
#pragma unroll
        for (int sidx = 0; sidx < NS; ++sidx) {
            float v = acc[sidx][j];
            s += v; q = fmaf(v, v, q);
            mx = fmaxf(mx, v); mn = fminf(mn, v);
        }
        bsum[ci][o] = s;
        bssq[ci][o] = q;
        ymax[m*COUT + o] = mx;
        ymin[m*COUT + o] = mn;
    }
    __syncthreads();
    if (t < COUT) {
        float s = bsum[0][t] + bsum[1][t] + bsum[2][t] + bsum[3][t];
        float q = bssq[0][t] + bssq[1][t] + bssq[2][t] + bssq[3][t];
        partials[blockIdx.x*256 + t]        = s;
        partials[blockIdx.x*256 + COUT + t] = q;
    }
}

// ---------------- BN stats reduce -> scale/shift ----------------
__global__ __launch_bounds__(256) void bnstat_kernel(const float* __restrict__ partials,
                                                     const float* __restrict__ gamma,
                                                     const float* __restrict__ beta,
                                                     float* __restrict__ scaleshift)
{
    __shared__ float ss[COUT], sq[COUT];
    int t = threadIdx.x;
    int ch = t & (COUT-1);
    int which = t >> 7;
    float a = 0.f;
    for (int b = 0; b < M_CTR/CPB; ++b) a += partials[b*256 + which*COUT + ch];
    if (which == 0) ss[ch] = a; else sq[ch] = a;
    __syncthreads();
    if (t < COUT) {
        const float inv = 1.0f / 65536.0f;
        float mean = ss[t] * inv;
        float var  = sq[t] * inv - mean*mean;
        float rstd = rsqrtf(var + 1e-5f);
        float g = gamma[t] * rstd;
        scaleshift[t]        = g;
        scaleshift[COUT + t] = beta[t] - mean * g;
    }
}

// ---------------- final: BN apply + ReLU on the pooled extreme ----------------
__global__ void final_kernel(float* __restrict__ y /* in: ymax, out: result */,
                             const float* __restrict__ ymin,
                             const float* __restrict__ scaleshift)
{
    int i = blockIdx.x * blockDim.x + threadIdx.x;
    if (i >= M_CTR * COUT) return;
    int o = i & (COUT - 1);
    float a = scaleshift[o], b = scaleshift[COUT + o];
    float v = (a >= 0.f) ? y[i] : ymin[i];
    float z = fmaf(a, v, b);
    y[i] = fmaxf(z, 0.f);
}

extern "C" void kernel_launch(void* const* d_in, const int* in_sizes, int n_in,
                              void* d_out, int out_size, void* d_ws, size_t ws_size,
                              hipStream_t stream)
{
    const float* p     = (const float*)d_in[0];
    const float* nrm   = (const float*)d_in[1];
    const float* xf    = (const float*)d_in[2];
    // d_in[3] = o (unused: single batch, static sizes)
    const float* W     = (const float*)d_in[4];
    const float* gamma = (const float*)d_in[5];
    const float* beta  = (const float*)d_in[6];
    float* out = (float*)d_out;

    char* ws = (char*)d_ws;
    int*   sel        = (int*)(ws + 0);            // 16 KB
    float* pp2        = (float*)(ws + 16384);      // 64 KB
    int*   knn        = (int*)(ws + 81920);        // 256 KB
    float* ymin       = (float*)(ws + 344064);     // 2 MB
    float* partials   = (float*)(ws + 2441216);    // 1 MB
    float* scaleshift = (float*)(ws + 3489792);    // 1 KB

    float* ymax = out + 24576;  // y region of d_out

    fps_kernel  <<<1,    1024, 0, stream>>>(p, sel);
    prep_kernel <<<64,   256,  0, stream>>>(p, nrm, sel, pp2, out);
    knn_kernel  <<<16,   256,  0, stream>>>(p, pp2, out, knn);
    passA_kernel<<<M_CTR/CPB, 128, 0, stream>>>(p, xf, W, knn, out, ymax, ymin, partials);
    bnstat_kernel<<<1,   256,  0, stream>>>(partials, gamma, beta, scaleshift);
    final_kernel<<<2048, 256,  0, stream>>>(ymax, ymin, scaleshift);
}

// Round 2
// 8313.493 us; speedup vs baseline: 1.5972x; 1.5972x over previous
//
#include <hip/hip_runtime.h>
#include <math.h>

#define N_PTS 16384
#define M_CTR 4096
#define NS 16
#define CIN 64
#define COUT 128
#define CFEAT 67
#define CPB 4          // centers per block in passA

// lexicographic (max v, tie -> min idx) combine
#define CMB_MAX(va, ia, vb, ib) do { \
    bool _b = ((vb) > (va)) || ((vb) == (va) && (ib) < (ia)); \
    (va) = _b ? (vb) : (va); (ia) = _b ? (ib) : (ia); \
} while (0)

// DPP argmax step: combine with lane-shifted (bv,bi); invalid lanes see identity
#define DPP_STEP(CTRL) do { \
    int _ovb = __builtin_amdgcn_update_dpp(0xbf800000, __float_as_int(bv), CTRL, 0xF, 0xF, false); \
    int _oib = __builtin_amdgcn_update_dpp(0x7fffffff, bi, CTRL, 0xF, 0xF, false); \
    float _ov = __int_as_float(_ovb); \
    CMB_MAX(bv, bi, _ov, _oib); \
} while (0)

// ---------------- FPS: single block, 512 threads, 32 pts/thread ----------------
__global__ __launch_bounds__(512) void fps_kernel(const float* __restrict__ p,
                                                  int* __restrict__ sel)
{
    const int tid = threadIdx.x;

    float px[32], py[32], pz[32], dist[32];
#pragma unroll
    for (int k = 0; k < 32; ++k) {
        int j = tid + (k << 9);
        px[k] = p[j*3+0]; py[k] = p[j*3+1]; pz[k] = p[j*3+2];
        dist[k] = 1e10f;
    }

    __shared__ float swv[2][8];
    __shared__ int   swi[2][8];

    if (tid == 0) sel[0] = 0;
    float qx = p[0], qy = p[1], qz = p[2];   // last = 0

    for (int it = 1; it < M_CTR; ++it) {
        // update dists + per-thread argmax (strict > with k ascending -> min global idx)
        float bv = -1.0f; int bk = 0;
#pragma unroll
        for (int k = 0; k < 32; ++k) {
            float dx = __fsub_rn(px[k], qx);
            float dy = __fsub_rn(py[k], qy);
            float dz = __fsub_rn(pz[k], qz);
            float d2 = __fadd_rn(__fadd_rn(__fmul_rn(dx,dx), __fmul_rn(dy,dy)),
                                 __fmul_rn(dz,dz));
            float nd = fminf(dist[k], d2);
            dist[k] = nd;
            bool b = nd > bv;
            bv = b ? nd : bv;
            bk = b ? k : bk;
        }
        int bi = tid + (bk << 9);

        // wave-level argmax via DPP (result lands in lane 63 of each wave)
        DPP_STEP(0x111);  // row_shr:1
        DPP_STEP(0x112);  // row_shr:2
        DPP_STEP(0x114);  // row_shr:4
        DPP_STEP(0x118);  // row_shr:8
        DPP_STEP(0x142);  // row_bcast15
        DPP_STEP(0x143);  // row_bcast31

        int par = it & 1;
        if ((tid & 63) == 63) { swv[par][tid >> 6] = bv; swi[par][tid >> 6] = bi; }
        __syncthreads();

        // all threads: tree-argmax over the 8 wave candidates
        float v0 = swv[par][0], v1 = swv[par][1], v2 = swv[par][2], v3 = swv[par][3];
        float v4 = swv[par][4], v5 = swv[par][5], v6 = swv[par][6], v7 = swv[par][7];
        int   j0 = swi[par][0], j1 = swi[par][1], j2 = swi[par][2], j3 = swi[par][3];
        int   j4 = swi[par][4], j5 = swi[par][5], j6 = swi[par][6], j7 = swi[par][7];
        CMB_MAX(v0, j0, v1, j1); CMB_MAX(v2, j2, v3, j3);
        CMB_MAX(v4, j4, v5, j5); CMB_MAX(v6, j6, v7, j7);
        CMB_MAX(v0, j0, v2, j2); CMB_MAX(v4, j4, v6, j6);
        CMB_MAX(v0, j0, v4, j4);
        int last = j0;

        if (tid == 0) sel[it] = last;

        // scalar fetch of next query point
        int ul = __builtin_amdgcn_readfirstlane(last);
        const float* q = p + ul * 3;
        qx = q[0]; qy = q[1]; qz = q[2];
    }
}

// ---------------- prep: pp2, gather n_p/n_n, write n_o ----------------
__global__ void prep_kernel(const float* __restrict__ p, const float* __restrict__ nrm,
                            const int* __restrict__ sel, float* __restrict__ pp2,
                            float* __restrict__ out)
{
    int i = blockIdx.x * blockDim.x + threadIdx.x;
    if (i < N_PTS) {
        float x = p[i*3], y = p[i*3+1], z = p[i*3+2];
        pp2[i] = __fadd_rn(__fadd_rn(__fmul_rn(x,x), __fmul_rn(y,y)), __fmul_rn(z,z));
    }
    if (i < M_CTR) {
        int j = sel[i];
        out[i*3+0] = p[j*3+0]; out[i*3+1] = p[j*3+1]; out[i*3+2] = p[j*3+2];
        out[12288 + i*3+0] = nrm[j*3+0];
        out[12288 + i*3+1] = nrm[j*3+1];
        out[12288 + i*3+2] = nrm[j*3+2];
    }
    if (i == 0) out[548864] = (float)M_CTR;   // n_o
}

// ---------------- kNN: one wave per center, per-lane sorted top-16 ----------------
__global__ __launch_bounds__(256) void knn_kernel(const float* __restrict__ p,
                                                  const float* __restrict__ pp2,
                                                  const float* __restrict__ np /* n_p */,
                                                  int* __restrict__ knn)
{
    const int lane = threadIdx.x & 63;
    const int wave = threadIdx.x >> 6;
    const int c = blockIdx.x * 4 + wave;

    float cx = np[c*3], cy = np[c*3+1], cz = np[c*3+2];
    float c2 = __fadd_rn(__fadd_rn(__fmul_rn(cx,cx), __fmul_rn(cy,cy)), __fmul_rn(cz,cz));

    float hd[16]; int hi[16];
#pragma unroll
    for (int k = 0; k < 16; ++k) { hd[k] = 1e30f; hi[k] = 0x7fffffff; }

    for (int t = 0; t < N_PTS/64; ++t) {
        int j = t*64 + lane;
        float px = p[j*3+0], py = p[j*3+1], pz = p[j*3+2];
        float dot = __fadd_rn(__fadd_rn(__fmul_rn(cx,px), __fmul_rn(cy,py)),
                              __fmul_rn(cz,pz));
        float d2  = __fsub_rn(__fadd_rn(c2, pp2[j]), __fmul_rn(2.0f, dot));
        if (d2 < hd[15]) {
            // stable predicated sorted insert (ascending; equal values keep earlier idx first)
#pragma unroll
            for (int k = 15; k >= 1; --k) {
                bool up   = d2 < hd[k-1];
                bool here = d2 < hd[k];
                hd[k] = up ? hd[k-1] : (here ? d2 : hd[k]);
                hi[k] = up ? hi[k-1] : (here ? j  : hi[k]);
            }
            if (d2 < hd[0]) { hd[0] = d2; hi[0] = j; }
        }
    }

    // merge 64 sorted lists: 16 rounds of wave-argmin (d2, then min idx)
    for (int r = 0; r < 16; ++r) {
        float wv = hd[0]; int wi = hi[0];
#pragma unroll
        for (int m = 1; m < 64; m <<= 1) {
            float ov = __shfl_xor(wv, m);
            int   oi = __shfl_xor(wi, m);
            bool b = (ov < wv) || (ov == wv && oi < wi);
            wv = b ? ov : wv; wi = b ? oi : wi;
        }
        if (hi[0] == wi) {
            knn[c*16 + r] = wi;
#pragma unroll
            for (int k = 0; k < 15; ++k) { hd[k] = hd[k+1]; hi[k] = hi[k+1]; }
            hd[15] = 1e30f; hi[15] = 0x7fffffff;
        }
    }
}

// ---------------- pass A: feat build + GEMM + stats + ymax/ymin ----------------
__global__ __launch_bounds__(128) void passA_kernel(const float* __restrict__ p,
                                                    const float* __restrict__ xf,
                                                    const float* __restrict__ W,
                                                    const int* __restrict__ knn,
                                                    const float* __restrict__ out /* n_p */,
                                                    float* __restrict__ ymax,   /* d_out y region */
                                                    float* __restrict__ ymin,
                                                    float* __restrict__ partials)
{
    __shared__ float Wt[CFEAT][COUT];
    __shared__ float ft[CPB][NS][CFEAT];
    __shared__ float bsum[CPB][COUT], bssq[CPB][COUT];

    const int t = threadIdx.x;
    const int mbase = blockIdx.x * CPB;

    for (int c = 0; c < CFEAT; ++c) Wt[c][t] = W[t*CFEAT + c];

    {
        int r = t >> 1, half = t & 1;
        int ci = r >> 4, s = r & 15;
        int m = mbase + ci;
        int nb = knn[m*NS + s];
        if (half == 0) {
            ft[ci][s][0] = __fsub_rn(p[nb*3+0], out[m*3+0]);
            ft[ci][s][1] = __fsub_rn(p[nb*3+1], out[m*3+1]);
            ft[ci][s][2] = __fsub_rn(p[nb*3+2], out[m*3+2]);
        }
        for (int c = half*32; c < half*32 + 32; ++c)
            ft[ci][s][3+c] = xf[nb*CIN + c];
    }
    __syncthreads();

    const int ci = t >> 5, l = t & 31;
    float acc[NS][4];
#pragma unroll
    for (int s = 0; s < NS; ++s) { acc[s][0]=0.f; acc[s][1]=0.f; acc[s][2]=0.f; acc[s][3]=0.f; }

    for (int c = 0; c < CFEAT; ++c) {
        float w0 = Wt[c][l], w1 = Wt[c][l+32], w2 = Wt[c][l+64], w3 = Wt[c][l+96];
#pragma unroll
        for (int s = 0; s < NS; ++s) {
            float f = ft[ci][s][c];
            acc[s][0] = fmaf(f, w0, acc[s][0]);
            acc[s][1] = fmaf(f, w1, acc[s][1]);
            acc[s][2] = fmaf(f, w2, acc[s][2]);
            acc[s][3] = fmaf(f, w3, acc[s][3]);
        }
    }

    const int m = mbase + ci;
#pragma unroll
    for (int j = 0; j < 4; ++j) {
        int o = l + 32*j;
        float s = 0.f, q = 0.f, mx = -1e30f, mn = 1e30f;
#pragma unroll
        for (int sidx = 0; sidx < NS; ++sidx) {
            float v = acc[sidx][j];
            s += v; q = fmaf(v, v, q);
            mx = fmaxf(mx, v); mn = fminf(mn, v);
        }
        bsum[ci][o] = s;
        bssq[ci][o] = q;
        ymax[m*COUT + o] = mx;
        ymin[m*COUT + o] = mn;
    }
    __syncthreads();
    if (t < COUT) {
        float s = bsum[0][t] + bsum[1][t] + bsum[2][t] + bsum[3][t];
        float q = bssq[0][t] + bssq[1][t] + bssq[2][t] + bssq[3][t];
        // slot-major layout: partials[slot][block], slot in [0,256)
        partials[t*1024         + blockIdx.x] = s;
        partials[(COUT + t)*1024 + blockIdx.x] = q;
    }
}

// ---------------- BN stats reduce -> scale/shift (coalesced-per-thread float4) ----------------
__global__ __launch_bounds__(256) void bnstat_kernel(const float* __restrict__ partials,
                                                     const float* __restrict__ gamma,
                                                     const float* __restrict__ beta,
                                                     float* __restrict__ scaleshift)
{
    __shared__ float red[256];
    int t = threadIdx.x;
    const float4* v4 = (const float4*)(partials + t*1024);
    float s = 0.f;
    for (int i = 0; i < 256; ++i) {
        float4 v = v4[i];
        s += v.x; s += v.y; s += v.z; s += v.w;   // ascending block order
    }
    red[t] = s;
    __syncthreads();
    if (t < COUT) {
        const float inv = 1.0f / 65536.0f;
        float mean = red[t] * inv;
        float var  = red[COUT + t] * inv - mean*mean;
        float rstd = rsqrtf(var + 1e-5f);
        float g = gamma[t] * rstd;
        scaleshift[t]        = g;
        scaleshift[COUT + t] = beta[t] - mean * g;
    }
}

// ---------------- final: BN apply + ReLU on the pooled extreme ----------------
__global__ void final_kernel(float* __restrict__ y /* in: ymax, out: result */,
                             const float* __restrict__ ymin,
                             const float* __restrict__ scaleshift)
{
    int i = blockIdx.x * blockDim.x + threadIdx.x;
    if (i >= M_CTR * COUT) return;
    int o = i & (COUT - 1);
    float a = scaleshift[o], b = scaleshift[COUT + o];
    float v = (a >= 0.f) ? y[i] : ymin[i];
    float z = fmaf(a, v, b);
    y[i] = fmaxf(z, 0.f);
}

extern "C" void kernel_launch(void* const* d_in, const int* in_sizes, int n_in,
                              void* d_out, int out_size, void* d_ws, size_t ws_size,
                              hipStream_t stream)
{
    const float* p     = (const float*)d_in[0];
    const float* nrm   = (const float*)d_in[1];
    const float* xf    = (const float*)d_in[2];
    // d_in[3] = o (unused: single batch, static sizes)
    const float* W     = (const float*)d_in[4];
    const float* gamma = (const float*)d_in[5];
    const float* beta  = (const float*)d_in[6];

    float* out = (float*)d_out;
    char* ws = (char*)d_ws;
    int*   sel        = (int*)(ws + 0);            // 16 KB
    float* pp2        = (float*)(ws + 16384);      // 64 KB
    int*   knn        = (int*)(ws + 81920);        // 256 KB
    float* ymin       = (float*)(ws + 344064);     // 2 MB
    float* partials   = (float*)(ws + 2441216);    // 1 MB (256 slots x 1024 blocks)
    float* scaleshift = (float*)(ws + 3489792);    // 1 KB

    float* ymax = out + 24576;  // y region of d_out

    fps_kernel  <<<1,    512,  0, stream>>>(p, sel);
    prep_kernel <<<64,   256,  0, stream>>>(p, nrm, sel, pp2, out);
    knn_kernel  <<<1024, 256,  0, stream>>>(p, pp2, out, knn);
    passA_kernel<<<M_CTR/CPB, 128, 0, stream>>>(p, xf, W, knn, out, ymax, ymin, partials);
    bnstat_kernel<<<1,   256,  0, stream>>>(partials, gamma, beta, scaleshift);
    final_kernel<<<2048, 256,  0, stream>>>(ymax, ymin, scaleshift);
}

// Round 3
// 7604.198 us; speedup vs baseline: 1.7461x; 1.0933x over previous
//
#include <hip/hip_runtime.h>
#include <math.h>

#define N_PTS 16384
#define M_CTR 4096
#define NS 16
#define CIN 64
#define COUT 128
#define CFEAT 67
#define CPB 4          // centers per block in passA

// lexicographic (max v, tie -> min idx) combine
#define CMB_MAX(va, ia, vb, ib) do { \
    bool _b = ((vb) > (va)) || ((vb) == (va) && (ib) < (ia)); \
    (va) = _b ? (vb) : (va); (ia) = _b ? (ib) : (ia); \
} while (0)

// DPP argmax step: combine with lane-shifted (bv,bi); invalid lanes see identity
#define DPP_STEP(CTRL) do { \
    int _ovb = __builtin_amdgcn_update_dpp(0xbf800000, __float_as_int(bv), CTRL, 0xF, 0xF, false); \
    int _oib = __builtin_amdgcn_update_dpp(0x7fffffff, bi, CTRL, 0xF, 0xF, false); \
    float _ov = __int_as_float(_ovb); \
    CMB_MAX(bv, bi, _ov, _oib); \
} while (0)

// ---------------- FPS: single block, 512 threads, 32 pts/thread, regs-resident ----------------
__global__ __launch_bounds__(512, 2) void fps_kernel(const float* __restrict__ p,
                                                     int* __restrict__ sel)
{
    const int tid = threadIdx.x;

    float px[32], py[32], pz[32], dist[32];
#pragma unroll
    for (int k = 0; k < 32; ++k) {
        int j = tid + (k << 9);
        px[k] = p[j*3+0]; py[k] = p[j*3+1]; pz[k] = p[j*3+2];
        dist[k] = 1e10f;
    }

    __shared__ float2 sw[2][8];

    if (tid == 0) sel[0] = 0;
    float qx = p[0], qy = p[1], qz = p[2];   // last = 0

    for (int it = 1; it < M_CTR; ++it) {
        // update dists + per-thread argmax; bk in [0,32) uses inline consts
        float bv = -1.0f; int bk = 0;
#pragma unroll
        for (int k = 0; k < 32; ++k) {
            float dx = __fsub_rn(px[k], qx);
            float dy = __fsub_rn(py[k], qy);
            float dz = __fsub_rn(pz[k], qz);
            float d2 = __fadd_rn(__fadd_rn(__fmul_rn(dx,dx), __fmul_rn(dy,dy)),
                                 __fmul_rn(dz,dz));
            float nd = fminf(dist[k], d2);
            dist[k] = nd;
            bool b = nd > bv;            // strict: k ascending -> min global idx per thread
            bv = b ? nd : bv;
            bk = b ? k : bk;
        }
        int bi = tid + (bk << 9);

        // wave-level argmax via DPP (result lands in lane 63 of each wave)
        DPP_STEP(0x111);  // row_shr:1
        DPP_STEP(0x112);  // row_shr:2
        DPP_STEP(0x114);  // row_shr:4
        DPP_STEP(0x118);  // row_shr:8
        DPP_STEP(0x142);  // row_bcast15
        DPP_STEP(0x143);  // row_bcast31

        int par = it & 1;
        if ((tid & 63) == 63) sw[par][tid >> 6] = make_float2(bv, __int_as_float(bi));
        __syncthreads();

        // all threads: tree-argmax over the 8 wave candidates (b64 broadcast reads)
        float2 c0 = sw[par][0], c1 = sw[par][1], c2 = sw[par][2], c3 = sw[par][3];
        float2 c4 = sw[par][4], c5 = sw[par][5], c6 = sw[par][6], c7 = sw[par][7];
        float v0 = c0.x, v1 = c1.x, v2 = c2.x, v3 = c3.x;
        float v4 = c4.x, v5 = c5.x, v6 = c6.x, v7 = c7.x;
        int   j0 = __float_as_int(c0.y), j1 = __float_as_int(c1.y);
        int   j2 = __float_as_int(c2.y), j3 = __float_as_int(c3.y);
        int   j4 = __float_as_int(c4.y), j5 = __float_as_int(c5.y);
        int   j6 = __float_as_int(c6.y), j7 = __float_as_int(c7.y);
        CMB_MAX(v0, j0, v1, j1); CMB_MAX(v2, j2, v3, j3);
        CMB_MAX(v4, j4, v5, j5); CMB_MAX(v6, j6, v7, j7);
        CMB_MAX(v0, j0, v2, j2); CMB_MAX(v4, j4, v6, j6);
        CMB_MAX(v0, j0, v4, j4);
        int last = j0;

        if (tid == 0) sel[it] = last;

        // scalar fetch of next query point (uniform -> s_load from L2)
        int ul = __builtin_amdgcn_readfirstlane(last);
        qx = p[ul*3+0]; qy = p[ul*3+1]; qz = p[ul*3+2];
    }
}

// ---------------- prep: pp2, gather n_p/n_n, write n_o ----------------
__global__ void prep_kernel(const float* __restrict__ p, const float* __restrict__ nrm,
                            const int* __restrict__ sel, float* __restrict__ pp2,
                            float* __restrict__ out)
{
    int i = blockIdx.x * blockDim.x + threadIdx.x;
    if (i < N_PTS) {
        float x = p[i*3], y = p[i*3+1], z = p[i*3+2];
        pp2[i] = __fadd_rn(__fadd_rn(__fmul_rn(x,x), __fmul_rn(y,y)), __fmul_rn(z,z));
    }
    if (i < M_CTR) {
        int j = sel[i];
        out[i*3+0] = p[j*3+0]; out[i*3+1] = p[j*3+1]; out[i*3+2] = p[j*3+2];
        out[12288 + i*3+0] = nrm[j*3+0];
        out[12288 + i*3+1] = nrm[j*3+1];
        out[12288 + i*3+2] = nrm[j*3+2];
    }
    if (i == 0) out[548864] = (float)M_CTR;   // n_o
}

// ---------------- kNN: one wave per center, per-lane sorted top-16 ----------------
__global__ __launch_bounds__(256) void knn_kernel(const float* __restrict__ p,
                                                  const float* __restrict__ pp2,
                                                  const float* __restrict__ np /* n_p */,
                                                  int* __restrict__ knn)
{
    const int lane = threadIdx.x & 63;
    const int wave = threadIdx.x >> 6;
    const int c = blockIdx.x * 4 + wave;

    float cx = np[c*3], cy = np[c*3+1], cz = np[c*3+2];
    float c2 = __fadd_rn(__fadd_rn(__fmul_rn(cx,cx), __fmul_rn(cy,cy)), __fmul_rn(cz,cz));

    float hd[16]; int hi[16];
#pragma unroll
    for (int k = 0; k < 16; ++k) { hd[k] = 1e30f; hi[k] = 0x7fffffff; }

    for (int t = 0; t < N_PTS/64; ++t) {
        int j = t*64 + lane;
        float px = p[j*3+0], py = p[j*3+1], pz = p[j*3+2];
        float dot = __fadd_rn(__fadd_rn(__fmul_rn(cx,px), __fmul_rn(cy,py)),
                              __fmul_rn(cz,pz));
        float d2  = __fsub_rn(__fadd_rn(c2, pp2[j]), __fmul_rn(2.0f, dot));
        if (d2 < hd[15]) {
            // stable predicated sorted insert (ascending; equal values keep earlier idx first)
#pragma unroll
            for (int k = 15; k >= 1; --k) {
                bool up   = d2 < hd[k-1];
                bool here = d2 < hd[k];
                hd[k] = up ? hd[k-1] : (here ? d2 : hd[k]);
                hi[k] = up ? hi[k-1] : (here ? j  : hi[k]);
            }
            if (d2 < hd[0]) { hd[0] = d2; hi[0] = j; }
        }
    }

    // merge 64 sorted lists: 16 rounds of wave-argmin (d2, then min idx)
    for (int r = 0; r < 16; ++r) {
        float wv = hd[0]; int wi = hi[0];
#pragma unroll
        for (int m = 1; m < 64; m <<= 1) {
            float ov = __shfl_xor(wv, m);
            int   oi = __shfl_xor(wi, m);
            bool b = (ov < wv) || (ov == wv && oi < wi);
            wv = b ? ov : wv; wi = b ? oi : wi;
        }
        if (hi[0] == wi) {
            knn[c*16 + r] = wi;
#pragma unroll
            for (int k = 0; k < 15; ++k) { hd[k] = hd[k+1]; hi[k] = hi[k+1]; }
            hd[15] = 1e30f; hi[15] = 0x7fffffff;
        }
    }
}

// ---------------- pass A: feat build + GEMM + stats + ymax/ymin ----------------
__global__ __launch_bounds__(128) void passA_kernel(const float* __restrict__ p,
                                                    const float* __restrict__ xf,
                                                    const float* __restrict__ W,
                                                    const int* __restrict__ knn,
                                                    const float* __restrict__ out /* n_p */,
                                                    float* __restrict__ ymax,   /* d_out y region */
                                                    float* __restrict__ ymin,
                                                    float* __restrict__ partials)
{
    __shared__ float Wt[CFEAT][COUT];
    __shared__ float ft[CPB][NS][CFEAT];
    __shared__ float bsum[CPB][COUT], bssq[CPB][COUT];

    const int t = threadIdx.x;
    const int mbase = blockIdx.x * CPB;

    for (int c = 0; c < CFEAT; ++c) Wt[c][t] = W[t*CFEAT + c];

    {
        int r = t >> 1, half = t & 1;
        int ci = r >> 4, s = r & 15;
        int m = mbase + ci;
        int nb = knn[m*NS + s];
        if (half == 0) {
            ft[ci][s][0] = __fsub_rn(p[nb*3+0], out[m*3+0]);
            ft[ci][s][1] = __fsub_rn(p[nb*3+1], out[m*3+1]);
            ft[ci][s][2] = __fsub_rn(p[nb*3+2], out[m*3+2]);
        }
        for (int c = half*32; c < half*32 + 32; ++c)
            ft[ci][s][3+c] = xf[nb*CIN + c];
    }
    __syncthreads();

    const int ci = t >> 5, l = t & 31;
    float acc[NS][4];
#pragma unroll
    for (int s = 0; s < NS; ++s) { acc[s][0]=0.f; acc[s][1]=0.f; acc[s][2]=0.f; acc[s][3]=0.f; }

    for (int c = 0; c < CFEAT; ++c) {
        float w0 = Wt[c][l], w1 = Wt[c][l+32], w2 = Wt[c][l+64], w3 = Wt[c][l+96];
#pragma unroll
        for (int s = 0; s < NS; ++s) {
            float f = ft[ci][s][c];
            acc[s][0] = fmaf(f, w0, acc[s][0]);
            acc[s][1] = fmaf(f, w1, acc[s][1]);
            acc[s][2] = fmaf(f, w2, acc[s][2]);
            acc[s][3] = fmaf(f, w3, acc[s][3]);
        }
    }

    const int m = mbase + ci;
#pragma unroll
    for (int j = 0; j < 4; ++j) {
        int o = l + 32*j;
        float s = 0.f, q = 0.f, mx = -1e30f, mn = 1e30f;
#pragma unroll
        for (int sidx = 0; sidx < NS; ++sidx) {
            float v = acc[sidx][j];
            s += v; q = fmaf(v, v, q);
            mx = fmaxf(mx, v); mn = fminf(mn, v);
        }
        bsum[ci][o] = s;
        bssq[ci][o] = q;
        ymax[m*COUT + o] = mx;
        ymin[m*COUT + o] = mn;
    }
    __syncthreads();
    if (t < COUT) {
        float s = bsum[0][t] + bsum[1][t] + bsum[2][t] + bsum[3][t];
        float q = bssq[0][t] + bssq[1][t] + bssq[2][t] + bssq[3][t];
        // slot-major layout: partials[slot][block], slot in [0,256)
        partials[t*1024          + blockIdx.x] = s;
        partials[(COUT + t)*1024 + blockIdx.x] = q;
    }
}

// ---------------- BN stats reduce -> scale/shift (coalesced-per-thread float4) ----------------
__global__ __launch_bounds__(256) void bnstat_kernel(const float* __restrict__ partials,
                                                     const float* __restrict__ gamma,
                                                     const float* __restrict__ beta,
                                                     float* __restrict__ scaleshift)
{
    __shared__ float red[256];
    int t = threadIdx.x;
    const float4* v4 = (const float4*)(partials + t*1024);
    float s = 0.f;
    for (int i = 0; i < 256; ++i) {
        float4 v = v4[i];
        s += v.x; s += v.y; s += v.z; s += v.w;   // ascending block order
    }
    red[t] = s;
    __syncthreads();
    if (t < COUT) {
        const float inv = 1.0f / 65536.0f;
        float mean = red[t] * inv;
        float var  = red[COUT + t] * inv - mean*mean;
        float rstd = rsqrtf(var + 1e-5f);
        float g = gamma[t] * rstd;
        scaleshift[t]        = g;
        scaleshift[COUT + t] = beta[t] - mean * g;
    }
}

// ---------------- final: BN apply + ReLU on the pooled extreme ----------------
__global__ void final_kernel(float* __restrict__ y /* in: ymax, out: result */,
                             const float* __restrict__ ymin,
                             const float* __restrict__ scaleshift)
{
    int i = blockIdx.x * blockDim.x + threadIdx.x;
    if (i >= M_CTR * COUT) return;
    int o = i & (COUT - 1);
    float a = scaleshift[o], b = scaleshift[COUT + o];
    float v = (a >= 0.f) ? y[i] : ymin[i];
    float z = fmaf(a, v, b);
    y[i] = fmaxf(z, 0.f);
}

extern "C" void kernel_launch(void* const* d_in, const int* in_sizes, int n_in,
                              void* d_out, int out_size, void* d_ws, size_t ws_size,
                              hipStream_t stream)
{
    const float* p     = (const float*)d_in[0];
    const float* nrm   = (const float*)d_in[1];
    const float* xf    = (const float*)d_in[2];
    // d_in[3] = o (unused: single batch, static sizes)
    const float* W     = (const float*)d_in[4];
    const float* gamma = (const float*)d_in[5];
    const float* beta  = (const float*)d_in[6];

    float* out = (float*)d_out;
    char* ws = (char*)d_ws;
    int*   sel        = (int*)(ws + 0);            // 16 KB
    float* pp2        = (float*)(ws + 16384);      // 64 KB
    int*   knn        = (int*)(ws + 81920);        // 256 KB
    float* ymin       = (float*)(ws + 344064);     // 2 MB
    float* partials   = (float*)(ws + 2441216);    // 1 MB (256 slots x 1024 blocks)
    float* scaleshift = (float*)(ws + 3489792);    // 1 KB

    float* ymax = out + 24576;  // y region of d_out

    fps_kernel  <<<1,    512,  0, stream>>>(p, sel);
    prep_kernel <<<64,   256,  0, stream>>>(p, nrm, sel, pp2, out);
    knn_kernel  <<<1024, 256,  0, stream>>>(p, pp2, out, knn);
    passA_kernel<<<M_CTR/CPB, 128, 0, stream>>>(p, xf, W, knn, out, ymax, ymin, partials);
    bnstat_kernel<<<1,   256,  0, stream>>>(partials, gamma, beta, scaleshift);
    final_kernel<<<2048, 256,  0, stream>>>(ymax, ymin, scaleshift);
}

// Round 4
// 7471.433 us; speedup vs baseline: 1.7772x; 1.0178x over previous
//
#include <hip/hip_runtime.h>
#include <math.h>

#define N_PTS 16384
#define M_CTR 4096
#define NS 16
#define CIN 64
#define COUT 128
#define CFEAT 67
#define CPB 4          // centers per block in passA

// lexicographic (max v, tie -> min idx) combine
#define CMB_MAX(va, ia, vb, ib) do { \
    bool _b = ((vb) > (va)) || ((vb) == (va) && (ib) < (ia)); \
    (va) = _b ? (vb) : (va); (ia) = _b ? (ib) : (ia); \
} while (0)

// DPP argmax step: combine with lane-shifted (bv,bi); invalid lanes see identity
#define DPP_STEP(CTRL) do { \
    int _ovb = __builtin_amdgcn_update_dpp(0xbf800000, __float_as_int(bv), CTRL, 0xF, 0xF, false); \
    int _oib = __builtin_amdgcn_update_dpp(0x7fffffff, bi, CTRL, 0xF, 0xF, false); \
    float _ov = __int_as_float(_ovb); \
    CMB_MAX(bv, bi, _ov, _oib); \
} while (0)

// ---------------- FPS: single block, 512 threads, 32 pts/thread, regs-resident ----------------
// waves_per_eu(2,2): 8 waves on this CU = exactly 2/EU; max=2 raises the RA's
// pressure target to 256 VGPR so the 128-float point/dist state stays in registers.
__global__ __attribute__((amdgpu_flat_work_group_size(512, 512)))
__attribute__((amdgpu_waves_per_eu(2, 2)))
void fps_kernel(const float* __restrict__ p, int* __restrict__ sel)
{
    const int tid = threadIdx.x;

    float px[32], py[32], pz[32], dist[32];
#pragma unroll
    for (int k = 0; k < 32; ++k) {
        int j = tid + (k << 9);
        px[k] = p[j*3+0]; py[k] = p[j*3+1]; pz[k] = p[j*3+2];
        dist[k] = 1e10f;
    }

    __shared__ float2 sw[2][8];

    if (tid == 0) sel[0] = 0;
    float qx = p[0], qy = p[1], qz = p[2];   // last = 0

    for (int it = 1; it < M_CTR; ++it) {
        // update dists + per-thread argmax; bk in [0,32) uses inline consts
        float bv = -1.0f; int bk = 0;
#pragma unroll
        for (int k = 0; k < 32; ++k) {
            float dx = __fsub_rn(px[k], qx);
            float dy = __fsub_rn(py[k], qy);
            float dz = __fsub_rn(pz[k], qz);
            float d2 = __fadd_rn(__fadd_rn(__fmul_rn(dx,dx), __fmul_rn(dy,dy)),
                                 __fmul_rn(dz,dz));
            float nd = fminf(dist[k], d2);
            dist[k] = nd;
            bool b = nd > bv;            // strict: k ascending -> min global idx per thread
            bv = b ? nd : bv;
            bk = b ? k : bk;
        }
        int bi = tid + (bk << 9);

        // wave-level argmax via DPP (result lands in lane 63 of each wave)
        DPP_STEP(0x111);  // row_shr:1
        DPP_STEP(0x112);  // row_shr:2
        DPP_STEP(0x114);  // row_shr:4
        DPP_STEP(0x118);  // row_shr:8
        DPP_STEP(0x142);  // row_bcast15
        DPP_STEP(0x143);  // row_bcast31

        int par = it & 1;
        if ((tid & 63) == 63) sw[par][tid >> 6] = make_float2(bv, __int_as_float(bi));
        __syncthreads();

        // all threads: tree-argmax over the 8 wave candidates (b64 broadcast reads)
        float2 c0 = sw[par][0], c1 = sw[par][1], c2 = sw[par][2], c3 = sw[par][3];
        float2 c4 = sw[par][4], c5 = sw[par][5], c6 = sw[par][6], c7 = sw[par][7];
        float v0 = c0.x, v1 = c1.x, v2 = c2.x, v3 = c3.x;
        float v4 = c4.x, v5 = c5.x, v6 = c6.x, v7 = c7.x;
        int   j0 = __float_as_int(c0.y), j1 = __float_as_int(c1.y);
        int   j2 = __float_as_int(c2.y), j3 = __float_as_int(c3.y);
        int   j4 = __float_as_int(c4.y), j5 = __float_as_int(c5.y);
        int   j6 = __float_as_int(c6.y), j7 = __float_as_int(c7.y);
        CMB_MAX(v0, j0, v1, j1); CMB_MAX(v2, j2, v3, j3);
        CMB_MAX(v4, j4, v5, j5); CMB_MAX(v6, j6, v7, j7);
        CMB_MAX(v0, j0, v2, j2); CMB_MAX(v4, j4, v6, j6);
        CMB_MAX(v0, j0, v4, j4);
        int last = j0;

        if (tid == 0) sel[it] = last;

        // scalar fetch of next query point (uniform -> s_load from L2)
        int ul = __builtin_amdgcn_readfirstlane(last);
        qx = p[ul*3+0]; qy = p[ul*3+1]; qz = p[ul*3+2];
    }
}

// ---------------- prep: pp2, gather n_p/n_n, write n_o ----------------
__global__ void prep_kernel(const float* __restrict__ p, const float* __restrict__ nrm,
                            const int* __restrict__ sel, float* __restrict__ pp2,
                            float* __restrict__ out)
{
    int i = blockIdx.x * blockDim.x + threadIdx.x;
    if (i < N_PTS) {
        float x = p[i*3], y = p[i*3+1], z = p[i*3+2];
        pp2[i] = __fadd_rn(__fadd_rn(__fmul_rn(x,x), __fmul_rn(y,y)), __fmul_rn(z,z));
    }
    if (i < M_CTR) {
        int j = sel[i];
        out[i*3+0] = p[j*3+0]; out[i*3+1] = p[j*3+1]; out[i*3+2] = p[j*3+2];
        out[12288 + i*3+0] = nrm[j*3+0];
        out[12288 + i*3+1] = nrm[j*3+1];
        out[12288 + i*3+2] = nrm[j*3+2];
    }
    if (i == 0) out[548864] = (float)M_CTR;   // n_o
}

// ---------------- kNN: one wave per center, per-lane sorted top-16 ----------------
__global__ __launch_bounds__(256) void knn_kernel(const float* __restrict__ p,
                                                  const float* __restrict__ pp2,
                                                  const float* __restrict__ np /* n_p */,
                                                  int* __restrict__ knn)
{
    const int lane = threadIdx.x & 63;
    const int wave = threadIdx.x >> 6;
    const int c = blockIdx.x * 4 + wave;

    float cx = np[c*3], cy = np[c*3+1], cz = np[c*3+2];
    float c2 = __fadd_rn(__fadd_rn(__fmul_rn(cx,cx), __fmul_rn(cy,cy)), __fmul_rn(cz,cz));

    float hd[16]; int hi[16];
#pragma unroll
    for (int k = 0; k < 16; ++k) { hd[k] = 1e30f; hi[k] = 0x7fffffff; }

    for (int t = 0; t < N_PTS/64; ++t) {
        int j = t*64 + lane;
        float px = p[j*3+0], py = p[j*3+1], pz = p[j*3+2];
        float dot = __fadd_rn(__fadd_rn(__fmul_rn(cx,px), __fmul_rn(cy,py)),
                              __fmul_rn(cz,pz));
        float d2  = __fsub_rn(__fadd_rn(c2, pp2[j]), __fmul_rn(2.0f, dot));
        if (d2 < hd[15]) {
            // stable predicated sorted insert (ascending; equal values keep earlier idx first)
#pragma unroll
            for (int k = 15; k >= 1; --k) {
                bool up   = d2 < hd[k-1];
                bool here = d2 < hd[k];
                hd[k] = up ? hd[k-1] : (here ? d2 : hd[k]);
                hi[k] = up ? hi[k-1] : (here ? j  : hi[k]);
            }
            if (d2 < hd[0]) { hd[0] = d2; hi[0] = j; }
        }
    }

    // merge 64 sorted lists: 16 rounds of wave-argmin (d2, then min idx)
    for (int r = 0; r < 16; ++r) {
        float wv = hd[0]; int wi = hi[0];
#pragma unroll
        for (int m = 1; m < 64; m <<= 1) {
            float ov = __shfl_xor(wv, m);
            int   oi = __shfl_xor(wi, m);
            bool b = (ov < wv) || (ov == wv && oi < wi);
            wv = b ? ov : wv; wi = b ? oi : wi;
        }
        if (hi[0] == wi) {
            knn[c*16 + r] = wi;
#pragma unroll
            for (int k = 0; k < 15; ++k) { hd[k] = hd[k+1]; hi[k] = hi[k+1]; }
            hd[15] = 1e30f; hi[15] = 0x7fffffff;
        }
    }
}

// ---------------- pass A: feat build + GEMM + stats + ymax/ymin ----------------
__global__ __launch_bounds__(128) void passA_kernel(const float* __restrict__ p,
                                                    const float* __restrict__ xf,
                                                    const float* __restrict__ W,
                                                    const int* __restrict__ knn,
                                                    const float* __restrict__ out /* n_p */,
                                                    float* __restrict__ ymax,   /* d_out y region */
                                                    float* __restrict__ ymin,
                                                    float* __restrict__ partials)
{
    __shared__ float Wt[CFEAT][COUT];
    __shared__ float ft[CPB][NS][CFEAT];
    __shared__ float bsum[CPB][COUT], bssq[CPB][COUT];

    const int t = threadIdx.x;
    const int mbase = blockIdx.x * CPB;

    for (int c = 0; c < CFEAT; ++c) Wt[c][t] = W[t*CFEAT + c];

    {
        int r = t >> 1, half = t & 1;
        int ci = r >> 4, s = r & 15;
        int m = mbase + ci;
        int nb = knn[m*NS + s];
        if (half == 0) {
            ft[ci][s][0] = __fsub_rn(p[nb*3+0], out[m*3+0]);
            ft[ci][s][1] = __fsub_rn(p[nb*3+1], out[m*3+1]);
            ft[ci][s][2] = __fsub_rn(p[nb*3+2], out[m*3+2]);
        }
        for (int c = half*32; c < half*32 + 32; ++c)
            ft[ci][s][3+c] = xf[nb*CIN + c];
    }
    __syncthreads();

    const int ci = t >> 5, l = t & 31;
    float acc[NS][4];
#pragma unroll
    for (int s = 0; s < NS; ++s) { acc[s][0]=0.f; acc[s][1]=0.f; acc[s][2]=0.f; acc[s][3]=0.f; }

    for (int c = 0; c < CFEAT; ++c) {
        float w0 = Wt[c][l], w1 = Wt[c][l+32], w2 = Wt[c][l+64], w3 = Wt[c][l+96];
#pragma unroll
        for (int s = 0; s < NS; ++s) {
            float f = ft[ci][s][c];
            acc[s][0] = fmaf(f, w0, acc[s][0]);
            acc[s][1] = fmaf(f, w1, acc[s][1]);
            acc[s][2] = fmaf(f, w2, acc[s][2]);
            acc[s][3] = fmaf(f, w3, acc[s][3]);
        }
    }

    const int m = mbase + ci;
#pragma unroll
    for (int j = 0; j < 4; ++j) {
        int o = l + 32*j;
        float s = 0.f, q = 0.f, mx = -1e30f, mn = 1e30f;
#pragma unroll
        for (int sidx = 0; sidx < NS; ++sidx) {
            float v = acc[sidx][j];
            s += v; q = fmaf(v, v, q);
            mx = fmaxf(mx, v); mn = fminf(mn, v);
        }
        bsum[ci][o] = s;
        bssq[ci][o] = q;
        ymax[m*COUT + o] = mx;
        ymin[m*COUT + o] = mn;
    }
    __syncthreads();
    if (t < COUT) {
        float s = bsum[0][t] + bsum[1][t] + bsum[2][t] + bsum[3][t];
        float q = bssq[0][t] + bssq[1][t] + bssq[2][t] + bssq[3][t];
        // slot-major layout: partials[slot][block], slot in [0,256)
        partials[t*1024          + blockIdx.x] = s;
        partials[(COUT + t)*1024 + blockIdx.x] = q;
    }
}

// ---------------- BN stats reduce -> scale/shift (coalesced-per-thread float4) ----------------
__global__ __launch_bounds__(256) void bnstat_kernel(const float* __restrict__ partials,
                                                     const float* __restrict__ gamma,
                                                     const float* __restrict__ beta,
                                                     float* __restrict__ scaleshift)
{
    __shared__ float red[256];
    int t = threadIdx.x;
    const float4* v4 = (const float4*)(partials + t*1024);
    float s = 0.f;
    for (int i = 0; i < 256; ++i) {
        float4 v = v4[i];
        s += v.x; s += v.y; s += v.z; s += v.w;   // ascending block order
    }
    red[t] = s;
    __syncthreads();
    if (t < COUT) {
        const float inv = 1.0f / 65536.0f;
        float mean = red[t] * inv;
        float var  = red[COUT + t] * inv - mean*mean;
        float rstd = rsqrtf(var + 1e-5f);
        float g = gamma[t] * rstd;
        scaleshift[t]        = g;
        scaleshift[COUT + t] = beta[t] - mean * g;
    }
}

// ---------------- final: BN apply + ReLU on the pooled extreme ----------------
__global__ void final_kernel(float* __restrict__ y /* in: ymax, out: result */,
                             const float* __restrict__ ymin,
                             const float* __restrict__ scaleshift)
{
    int i = blockIdx.x * blockDim.x + threadIdx.x;
    if (i >= M_CTR * COUT) return;
    int o = i & (COUT - 1);
    float a = scaleshift[o], b = scaleshift[COUT + o];
    float v = (a >= 0.f) ? y[i] : ymin[i];
    float z = fmaf(a, v, b);
    y[i] = fmaxf(z, 0.f);
}

extern "C" void kernel_launch(void* const* d_in, const int* in_sizes, int n_in,
                              void* d_out, int out_size, void* d_ws, size_t ws_size,
                              hipStream_t stream)
{
    const float* p     = (const float*)d_in[0];
    const float* nrm   = (const float*)d_in[1];
    const float* xf    = (const float*)d_in[2];
    // d_in[3] = o (unused: single batch, static sizes)
    const float* W     = (const float*)d_in[4];
    const float* gamma = (const float*)d_in[5];
    const float* beta  = (const float*)d_in[6];

    float* out = (float*)d_out;
    char* ws = (char*)d_ws;
    int*   sel        = (int*)(ws + 0);            // 16 KB
    float* pp2        = (float*)(ws + 16384);      // 64 KB
    int*   knn        = (int*)(ws + 81920);        // 256 KB
    float* ymin       = (float*)(ws + 344064);     // 2 MB
    float* partials   = (float*)(ws + 2441216);    // 1 MB (256 slots x 1024 blocks)
    float* scaleshift = (float*)(ws + 3489792);    // 1 KB

    float* ymax = out + 24576;  // y region of d_out

    fps_kernel  <<<1,    512,  0, stream>>>(p, sel);
    prep_kernel <<<64,   256,  0, stream>>>(p, nrm, sel, pp2, out);
    knn_kernel  <<<1024, 256,  0, stream>>>(p, pp2, out, knn);
    passA_kernel<<<M_CTR/CPB, 128, 0, stream>>>(p, xf, W, knn, out, ymax, ymin, partials);
    bnstat_kernel<<<1,   256,  0, stream>>>(partials, gamma, beta, scaleshift);
    final_kernel<<<2048, 256,  0, stream>>>(ymax, ymin, scaleshift);
}

// Round 5
// 7460.673 us; speedup vs baseline: 1.7797x; 1.0014x over previous
//
#include <hip/hip_runtime.h>
#include <math.h>

#define N_PTS 16384
#define M_CTR 4096
#define NS 16
#define CIN 64
#define COUT 128
#define CFEAT 67
#define CPB 4          // centers per block in passA

// lexicographic (max v, tie -> min idx) combine
#define CMB_MAX(va, ia, vb, ib) do { \
    bool _b = ((vb) > (va)) || ((vb) == (va) && (ib) < (ia)); \
    (va) = _b ? (vb) : (va); (ia) = _b ? (ib) : (ia); \
} while (0)

// DPP argmax step: combine with lane-shifted (bv,bi); invalid lanes see identity
#define DPP_STEP(CTRL) do { \
    int _ovb = __builtin_amdgcn_update_dpp(0xbf800000, __float_as_int(bv), CTRL, 0xF, 0xF, false); \
    int _oib = __builtin_amdgcn_update_dpp(0x7fffffff, bi, CTRL, 0xF, 0xF, false); \
    float _ov = __int_as_float(_ovb); \
    CMB_MAX(bv, bi, _ov, _oib); \
} while (0)

#define REPEAT32(M) M(0) M(1) M(2) M(3) M(4) M(5) M(6) M(7) \
                    M(8) M(9) M(10) M(11) M(12) M(13) M(14) M(15) \
                    M(16) M(17) M(18) M(19) M(20) M(21) M(22) M(23) \
                    M(24) M(25) M(26) M(27) M(28) M(29) M(30) M(31)

// ---------------- FPS: single block, 512 threads, 32 pts/thread ----------------
// State is 128 NAMED scalars (no arrays -> no SROA/unroll failure -> no scratch).
// waves_per_eu(2,2): 8 waves on this one CU = exactly 2/EU; RA budget 256 VGPR.
__global__ __attribute__((amdgpu_flat_work_group_size(512, 512)))
__attribute__((amdgpu_waves_per_eu(2, 2)))
void fps_kernel(const float* __restrict__ p, int* __restrict__ sel)
{
    const int tid = threadIdx.x;

#define DECL(k) float px##k, py##k, pz##k, ds##k;
    REPEAT32(DECL)
#undef DECL

#define INIT(k) { int j = tid + (k << 9); \
    px##k = p[j*3+0]; py##k = p[j*3+1]; pz##k = p[j*3+2]; ds##k = 1e10f; }
    REPEAT32(INIT)
#undef INIT

    __shared__ float2 sw[2][8];

    if (tid == 0) sel[0] = 0;
    float qx = p[0], qy = p[1], qz = p[2];   // last = 0

    for (int it = 1; it < M_CTR; ++it) {
        float bv = -1.0f; int bk = 0;
        // update dists + per-thread argmax; strict > with k ascending -> min idx
#define UPD(k) { \
        float dx = __fsub_rn(px##k, qx); \
        float dy = __fsub_rn(py##k, qy); \
        float dz = __fsub_rn(pz##k, qz); \
        float d2 = __fadd_rn(__fadd_rn(__fmul_rn(dx,dx), __fmul_rn(dy,dy)), \
                             __fmul_rn(dz,dz)); \
        float nd = fminf(ds##k, d2); \
        ds##k = nd; \
        bool b = nd > bv; \
        bv = b ? nd : bv; \
        bk = b ? k : bk; }
        REPEAT32(UPD)
#undef UPD
        int bi = tid + (bk << 9);

        // wave-level argmax via DPP (result lands in lane 63 of each wave)
        DPP_STEP(0x111);  // row_shr:1
        DPP_STEP(0x112);  // row_shr:2
        DPP_STEP(0x114);  // row_shr:4
        DPP_STEP(0x118);  // row_shr:8
        DPP_STEP(0x142);  // row_bcast15
        DPP_STEP(0x143);  // row_bcast31

        int par = it & 1;
        if ((tid & 63) == 63) sw[par][tid >> 6] = make_float2(bv, __int_as_float(bi));
        __syncthreads();

        // all threads: tree-argmax over the 8 wave candidates (b64 broadcast reads)
        float2 c0 = sw[par][0], c1 = sw[par][1], c2 = sw[par][2], c3 = sw[par][3];
        float2 c4 = sw[par][4], c5 = sw[par][5], c6 = sw[par][6], c7 = sw[par][7];
        float v0 = c0.x, v1 = c1.x, v2 = c2.x, v3 = c3.x;
        float v4 = c4.x, v5 = c5.x, v6 = c6.x, v7 = c7.x;
        int   j0 = __float_as_int(c0.y), j1 = __float_as_int(c1.y);
        int   j2 = __float_as_int(c2.y), j3 = __float_as_int(c3.y);
        int   j4 = __float_as_int(c4.y), j5 = __float_as_int(c5.y);
        int   j6 = __float_as_int(c6.y), j7 = __float_as_int(c7.y);
        CMB_MAX(v0, j0, v1, j1); CMB_MAX(v2, j2, v3, j3);
        CMB_MAX(v4, j4, v5, j5); CMB_MAX(v6, j6, v7, j7);
        CMB_MAX(v0, j0, v2, j2); CMB_MAX(v4, j4, v6, j6);
        CMB_MAX(v0, j0, v4, j4);
        int last = j0;

        if (tid == 0) sel[it] = last;

        // scalar fetch of next query point (uniform -> SMEM/L2)
        int ul = __builtin_amdgcn_readfirstlane(last);
        qx = p[ul*3+0]; qy = p[ul*3+1]; qz = p[ul*3+2];
    }
}

// ---------------- prep: pp2, gather n_p/n_n, write n_o ----------------
__global__ void prep_kernel(const float* __restrict__ p, const float* __restrict__ nrm,
                            const int* __restrict__ sel, float* __restrict__ pp2,
                            float* __restrict__ out)
{
    int i = blockIdx.x * blockDim.x + threadIdx.x;
    if (i < N_PTS) {
        float x = p[i*3], y = p[i*3+1], z = p[i*3+2];
        pp2[i] = __fadd_rn(__fadd_rn(__fmul_rn(x,x), __fmul_rn(y,y)), __fmul_rn(z,z));
    }
    if (i < M_CTR) {
        int j = sel[i];
        out[i*3+0] = p[j*3+0]; out[i*3+1] = p[j*3+1]; out[i*3+2] = p[j*3+2];
        out[12288 + i*3+0] = nrm[j*3+0];
        out[12288 + i*3+1] = nrm[j*3+1];
        out[12288 + i*3+2] = nrm[j*3+2];
    }
    if (i == 0) out[548864] = (float)M_CTR;   // n_o
}

// ---------------- kNN: one wave per center, per-lane sorted top-16 ----------------
__global__ __launch_bounds__(256) void knn_kernel(const float* __restrict__ p,
                                                  const float* __restrict__ pp2,
                                                  const float* __restrict__ np /* n_p */,
                                                  int* __restrict__ knn)
{
    const int lane = threadIdx.x & 63;
    const int wave = threadIdx.x >> 6;
    const int c = blockIdx.x * 4 + wave;

    float cx = np[c*3], cy = np[c*3+1], cz = np[c*3+2];
    float c2 = __fadd_rn(__fadd_rn(__fmul_rn(cx,cx), __fmul_rn(cy,cy)), __fmul_rn(cz,cz));

    float hd[16]; int hi[16];
#pragma unroll
    for (int k = 0; k < 16; ++k) { hd[k] = 1e30f; hi[k] = 0x7fffffff; }

    for (int t = 0; t < N_PTS/64; ++t) {
        int j = t*64 + lane;
        float px = p[j*3+0], py = p[j*3+1], pz = p[j*3+2];
        float dot = __fadd_rn(__fadd_rn(__fmul_rn(cx,px), __fmul_rn(cy,py)),
                              __fmul_rn(cz,pz));
        float d2  = __fsub_rn(__fadd_rn(c2, pp2[j]), __fmul_rn(2.0f, dot));
        if (d2 < hd[15]) {
            // stable predicated sorted insert (ascending; equal values keep earlier idx first)
#pragma unroll
            for (int k = 15; k >= 1; --k) {
                bool up   = d2 < hd[k-1];
                bool here = d2 < hd[k];
                hd[k] = up ? hd[k-1] : (here ? d2 : hd[k]);
                hi[k] = up ? hi[k-1] : (here ? j  : hi[k]);
            }
            if (d2 < hd[0]) { hd[0] = d2; hi[0] = j; }
        }
    }

    // merge 64 sorted lists: 16 rounds of wave-argmin (d2, then min idx)
    for (int r = 0; r < 16; ++r) {
        float wv = hd[0]; int wi = hi[0];
#pragma unroll
        for (int m = 1; m < 64; m <<= 1) {
            float ov = __shfl_xor(wv, m);
            int   oi = __shfl_xor(wi, m);
            bool b = (ov < wv) || (ov == wv && oi < wi);
            wv = b ? ov : wv; wi = b ? oi : wi;
        }
        if (hi[0] == wi) {
            knn[c*16 + r] = wi;
#pragma unroll
            for (int k = 0; k < 15; ++k) { hd[k] = hd[k+1]; hi[k] = hi[k+1]; }
            hd[15] = 1e30f; hi[15] = 0x7fffffff;
        }
    }
}

// ---------------- pass A: feat build + GEMM + stats + ymax/ymin ----------------
__global__ __launch_bounds__(128) void passA_kernel(const float* __restrict__ p,
                                                    const float* __restrict__ xf,
                                                    const float* __restrict__ W,
                                                    const int* __restrict__ knn,
                                                    const float* __restrict__ out /* n_p */,
                                                    float* __restrict__ ymax,   /* d_out y region */
                                                    float* __restrict__ ymin,
                                                    float* __restrict__ partials)
{
    __shared__ float Wt[CFEAT][COUT];
    __shared__ float ft[CPB][NS][CFEAT];
    __shared__ float bsum[CPB][COUT], bssq[CPB][COUT];

    const int t = threadIdx.x;
    const int mbase = blockIdx.x * CPB;

    for (int c = 0; c < CFEAT; ++c) Wt[c][t] = W[t*CFEAT + c];

    {
        int r = t >> 1, half = t & 1;
        int ci = r >> 4, s = r & 15;
        int m = mbase + ci;
        int nb = knn[m*NS + s];
        if (half == 0) {
            ft[ci][s][0] = __fsub_rn(p[nb*3+0], out[m*3+0]);
            ft[ci][s][1] = __fsub_rn(p[nb*3+1], out[m*3+1]);
            ft[ci][s][2] = __fsub_rn(p[nb*3+2], out[m*3+2]);
        }
        for (int c = half*32; c < half*32 + 32; ++c)
            ft[ci][s][3+c] = xf[nb*CIN + c];
    }
    __syncthreads();

    const int ci = t >> 5, l = t & 31;
    float acc[NS][4];
#pragma unroll
    for (int s = 0; s < NS; ++s) { acc[s][0]=0.f; acc[s][1]=0.f; acc[s][2]=0.f; acc[s][3]=0.f; }

    for (int c = 0; c < CFEAT; ++c) {
        float w0 = Wt[c][l], w1 = Wt[c][l+32], w2 = Wt[c][l+64], w3 = Wt[c][l+96];
#pragma unroll
        for (int s = 0; s < NS; ++s) {
            float f = ft[ci][s][c];
            acc[s][0] = fmaf(f, w0, acc[s][0]);
            acc[s][1] = fmaf(f, w1, acc[s][1]);
            acc[s][2] = fmaf(f, w2, acc[s][2]);
            acc[s][3] = fmaf(f, w3, acc[s][3]);
        }
    }

    const int m = mbase + ci;
#pragma unroll
    for (int j = 0; j < 4; ++j) {
        int o = l + 32*j;
        float s = 0.f, q = 0.f, mx = -1e30f, mn = 1e30f;
#pragma unroll
        for (int sidx = 0; sidx < NS; ++sidx) {
            float v = acc[sidx][j];
            s += v; q = fmaf(v, v, q);
            mx = fmaxf(mx, v); mn = fminf(mn, v);
        }
        bsum[ci][o] = s;
        bssq[ci][o] = q;
        ymax[m*COUT + o] = mx;
        ymin[m*COUT + o] = mn;
    }
    __syncthreads();
    if (t < COUT) {
        float s = bsum[0][t] + bsum[1][t] + bsum[2][t] + bsum[3][t];
        float q = bssq[0][t] + bssq[1][t] + bssq[2][t] + bssq[3][t];
        // slot-major layout: partials[slot][block], slot in [0,256)
        partials[t*1024          + blockIdx.x] = s;
        partials[(COUT + t)*1024 + blockIdx.x] = q;
    }
}

// ---------------- BN stats reduce -> scale/shift (coalesced-per-thread float4) ----------------
__global__ __launch_bounds__(256) void bnstat_kernel(const float* __restrict__ partials,
                                                     const float* __restrict__ gamma,
                                                     const float* __restrict__ beta,
                                                     float* __restrict__ scaleshift)
{
    __shared__ float red[256];
    int t = threadIdx.x;
    const float4* v4 = (const float4*)(partials + t*1024);
    float s = 0.f;
    for (int i = 0; i < 256; ++i) {
        float4 v = v4[i];
        s += v.x; s += v.y; s += v.z; s += v.w;   // ascending block order
    }
    red[t] = s;
    __syncthreads();
    if (t < COUT) {
        const float inv = 1.0f / 65536.0f;
        float mean = red[t] * inv;
        float var  = red[COUT + t] * inv - mean*mean;
        float rstd = rsqrtf(var + 1e-5f);
        float g = gamma[t] * rstd;
        scaleshift[t]        = g;
        scaleshift[COUT + t] = beta[t] - mean * g;
    }
}

// ---------------- final: BN apply + ReLU on the pooled extreme ----------------
__global__ void final_kernel(float* __restrict__ y /* in: ymax, out: result */,
                             const float* __restrict__ ymin,
                             const float* __restrict__ scaleshift)
{
    int i = blockIdx.x * blockDim.x + threadIdx.x;
    if (i >= M_CTR * COUT) return;
    int o = i & (COUT - 1);
    float a = scaleshift[o], b = scaleshift[COUT + o];
    float v = (a >= 0.f) ? y[i] : ymin[i];
    float z = fmaf(a, v, b);
    y[i] = fmaxf(z, 0.f);
}

extern "C" void kernel_launch(void* const* d_in, const int* in_sizes, int n_in,
                              void* d_out, int out_size, void* d_ws, size_t ws_size,
                              hipStream_t stream)
{
    const float* p     = (const float*)d_in[0];
    const float* nrm   = (const float*)d_in[1];
    const float* xf    = (const float*)d_in[2];
    // d_in[3] = o (unused: single batch, static sizes)
    const float* W     = (const float*)d_in[4];
    const float* gamma = (const float*)d_in[5];
    const float* beta  = (const float*)d_in[6];

    float* out = (float*)d_out;
    char* ws = (char*)d_ws;
    int*   sel        = (int*)(ws + 0);            // 16 KB
    float* pp2        = (float*)(ws + 16384);      // 64 KB
    int*   knn        = (int*)(ws + 81920);        // 256 KB
    float* ymin       = (float*)(ws + 344064);     // 2 MB
    float* partials   = (float*)(ws + 2441216);    // 1 MB (256 slots x 1024 blocks)
    float* scaleshift = (float*)(ws + 3489792);    // 1 KB

    float* ymax = out + 24576;  // y region of d_out

    fps_kernel  <<<1,    512,  0, stream>>>(p, sel);
    prep_kernel <<<64,   256,  0, stream>>>(p, nrm, sel, pp2, out);
    knn_kernel  <<<1024, 256,  0, stream>>>(p, pp2, out, knn);
    passA_kernel<<<M_CTR/CPB, 128, 0, stream>>>(p, xf, W, knn, out, ymax, ymin, partials);
    bnstat_kernel<<<1,   256,  0, stream>>>(partials, gamma, beta, scaleshift);
    final_kernel<<<2048, 256,  0, stream>>>(ymax, ymin, scaleshift);
}